// Round 7
// baseline (119.417 us; speedup 1.0000x reference)
//
#include <hip/hip_runtime.h>

// SecConv2d over Z_{2^32} via i8 MFMA, 4-chain biased-operand scheme (exact).
//   X = al + 256*ah + 32896   (al,ah = x bytes ^0x80, signed i8)
//   W = s0 + 256*s1 + 32896   (s0,s1 = w bytes ^0x80, signed i8)
//   out = P00 + (P01+P10)<<8 + P11<<16          (4 MFMA chains)
//       + 32896*Q[p]                            (Q = 3x3 box sum of S[p])
//       + K[k]                                  (per-k constant)
//   S[p] = sum_c (al+256*ah)[c,p]  (precomputed by packx, incl. border cells)
//   K[k] = bias[k] + 32896*sum(s0+256*s1) + 576*32896^2   (mod 2^32)
//
// secconv: block = 2 output rows x 56 cols, 4 waves = (ktile-pair kp x
// ptile-half ph). Each wave holds 2 k-tiles' A-frags resident (144 VGPR),
// so each pixel-tile's B-frags are read by only 2 waves (ds traffic halved
// vs R6). One stage + one barrier per block.

typedef int v4i __attribute__((ext_vector_type(4)));

#define XP   (58 * 58 * 128)   // bytes per packed image (al|ah interleaved)
#define ROWB (58 * 128)        // 7424 B per packed row
#define LCOL 144               // LDS col stride (128 + 16 pad)
#define LROW (58 * LCOL)       // 8352 B per LDS row

__device__ __align__(16) unsigned char g_xp[32 * XP];      // 13.8 MB
__device__ int g_sp[32 * 3364];                            // S-plane, padded
__device__ __align__(16) unsigned char g_wb[2 * 9 * 64 * 64];
__device__ unsigned g_off[64];

__global__ __launch_bounds__(256) void packx(const int* __restrict__ x) {
    int gid = blockIdx.x * 256 + threadIdx.x;   // (n,p): 32*3364 = 107648
    if (gid >= 32 * 3364) return;
    int p = gid % 3364;
    int n = gid / 3364;
    int pr = p / 58, pc = p - pr * 58;
    int ih = pr - 1, iw = pc - 1;
    unsigned char* ob = g_xp + (long)n * XP + (long)p * 128;
    int S;
    if ((unsigned)ih < 56u && (unsigned)iw < 56u) {
        const int* xp = x + (long)n * 64 * 3136 + ih * 56 + iw;
        unsigned lo[16], hi[16];
        int s = 0;
#pragma unroll
        for (int wd = 0; wd < 16; ++wd) {
            unsigned l = 0, h = 0;
#pragma unroll
            for (int j = 0; j < 4; ++j) {
                unsigned v = (unsigned)xp[(long)(wd * 4 + j) * 3136];
                s += (int)(v & 0xFFFFu);
                l |= (((v      ) & 0xFFu) ^ 0x80u) << (8 * j);
                h |= (((v >>  8) & 0xFFu) ^ 0x80u) << (8 * j);
            }
            lo[wd] = l; hi[wd] = h;
        }
#pragma unroll
        for (int q = 0; q < 4; ++q) {
            *(uint4*)(ob + 16 * q)      = make_uint4(lo[4*q], lo[4*q+1], lo[4*q+2], lo[4*q+3]);
            *(uint4*)(ob + 64 + 16 * q) = make_uint4(hi[4*q], hi[4*q+1], hi[4*q+2], hi[4*q+3]);
        }
        S = s - 2105344;                 // -64*32896
    } else {
        uint4 v = make_uint4(0x80808080u, 0x80808080u, 0x80808080u, 0x80808080u);
#pragma unroll
        for (int q = 0; q < 4; ++q) {
            *(uint4*)(ob + 16 * q)      = v;
            *(uint4*)(ob + 64 + 16 * q) = v;
        }
        S = -2105344;
    }
    g_sp[gid] = S;
}

__global__ __launch_bounds__(256) void packw(const int* __restrict__ w,
                                             const int* __restrict__ bias) {
    int blk = blockIdx.x;
    if (blk < 144) {
        int i = blk * 256 + threadIdx.x;        // [k][c][t] flat, 36864
        if (i >= 64 * 64 * 9) return;
        int k = i / 576;
        int r = i - k * 576;
        int c = r / 9;
        int t = r - c * 9;
        unsigned v = (unsigned)w[i];
        g_wb[((0 * 9 + t) * 64 + k) * 64 + c] = (unsigned char)((v & 255u) ^ 0x80u);
        g_wb[((1 * 9 + t) * 64 + k) * 64 + c] = (unsigned char)(((v >> 8) & 255u) ^ 0x80u);
    } else if (threadIdx.x < 64) {
        int k = threadIdx.x;
        int s0 = 0, s1 = 0;
        for (int j = 0; j < 576; ++j) {
            unsigned W = (unsigned)w[k * 576 + j];
            s0 += (int)(W & 255u);
            s1 += (int)((W >> 8) & 255u);
        }
        s0 -= 73728;                     // -128*576
        s1 -= 73728;
        unsigned ws = (unsigned)(s0 + 256 * s1);
        g_off[k] = (unsigned)bias[k] + 32896u * ws + 1082146816u * 576u;
    }
}

__global__ __launch_bounds__(256, 2) void secconv(int* __restrict__ out) {
    __shared__ unsigned char sx[4 * LROW];      // 33408 B
    __shared__ int ss[4 * 58];                  // S-plane rows

    const int tid  = threadIdx.x;
    const int blk  = blockIdx.x;                // 896 = 8 xcd * 112
    const int q    = blk >> 3;
    const int rp   = q % 28;                    // output row-pair
    const int n    = (blk & 7) + 8 * (q / 28);
    const int wid  = tid >> 6;
    const int lane = tid & 63;
    const int lm   = lane & 15;
    const int lq   = lane >> 4;
    const int kp   = wid & 1;                   // ktile-pair -> k base kp*32
    const int ph   = wid >> 1;                  // ptile half
    const int kbase = kp * 32;

    // ---- stage 4 padded rows of packed bytes + S values ----
    const unsigned char* gp = g_xp + (long)n * XP + (long)(2 * rp) * ROWB;
#pragma unroll
    for (int s = 0; s < 8; ++s) {
        int i = tid + s * 256;                  // 16B chunks, 1856 total
        if (i < 1856) {
            uint4 v = *(const uint4*)(gp + 16 * i);
            int grow = i / 464;
            int j    = i - grow * 464;
            int gcol = j >> 3, sub = j & 7;
            *(uint4*)(sx + grow * LROW + gcol * LCOL + sub * 16) = v;
        }
    }
    if (tid < 232)
        ss[tid] = g_sp[n * 3364 + (2 * rp) * 58 + tid];

    // ---- resident weight fragments: 2 ktiles x 2 limbs x 9 taps ----
    v4i wf[2][2][9];
#pragma unroll
    for (int kt = 0; kt < 2; ++kt)
#pragma unroll
        for (int l = 0; l < 2; ++l)
#pragma unroll
            for (int t = 0; t < 9; ++t)
                wf[kt][l][t] = *(const v4i*)(g_wb +
                    ((l * 9 + t) * 64 + (kbase + kt * 16 + lm)) * 64 + lq * 16);
    unsigned offv[2][4];
#pragma unroll
    for (int kt = 0; kt < 2; ++kt)
#pragma unroll
        for (int r = 0; r < 4; ++r)
            offv[kt][r] = g_off[kbase + kt * 16 + lq * 4 + r];

    __syncthreads();

    const int r8 = lm >> 3, c8 = lm & 7;        // pixel tile: 2 rows x 8 cols
    const unsigned char* lbase = sx + r8 * LROW + c8 * LCOL + lq * 16;

    const int t0 = ph ? 4 : 0, t1 = ph ? 7 : 4;
    for (int t = t0; t < t1; ++t) {
        const unsigned char* tb = lbase + t * 8 * LCOL;
        v4i a00[2] = {{0,0,0,0},{0,0,0,0}}, a01[2] = {{0,0,0,0},{0,0,0,0}};
        v4i a10[2] = {{0,0,0,0},{0,0,0,0}}, a11[2] = {{0,0,0,0},{0,0,0,0}};
#pragma unroll
        for (int tap = 0; tap < 9; ++tap) {
            const int dr = tap / 3, dc = tap - (tap / 3) * 3;
            const unsigned char* pp = tb + dr * LROW + dc * LCOL;
            v4i bl = *(const v4i*)(pp);
            v4i bh = *(const v4i*)(pp + 64);
#pragma unroll
            for (int kt = 0; kt < 2; ++kt) {
                a00[kt] = __builtin_amdgcn_mfma_i32_16x16x64_i8(wf[kt][0][tap], bl, a00[kt], 0, 0, 0);
                a01[kt] = __builtin_amdgcn_mfma_i32_16x16x64_i8(wf[kt][0][tap], bh, a01[kt], 0, 0, 0);
                a10[kt] = __builtin_amdgcn_mfma_i32_16x16x64_i8(wf[kt][1][tap], bl, a10[kt], 0, 0, 0);
                a11[kt] = __builtin_amdgcn_mfma_i32_16x16x64_i8(wf[kt][1][tap], bh, a11[kt], 0, 0, 0);
            }
        }

        // Q = 3x3 box sum of S at this lane's pixel
        const int pc = t * 8 + c8;
        int Q = 0;
#pragma unroll
        for (int dr = 0; dr < 3; ++dr)
#pragma unroll
            for (int dc = 0; dc < 3; ++dc)
                Q += ss[(r8 + dr) * 58 + pc + dc];
        const unsigned qq = 32896u * (unsigned)Q;

        const long pix = (long)(2 * rp + r8) * 56 + pc;
#pragma unroll
        for (int kt = 0; kt < 2; ++kt) {
            const long ob = ((long)n * 64 + kbase + kt * 16 + lq * 4) * 3136 + pix;
#pragma unroll
            for (int r = 0; r < 4; ++r) {
                unsigned val = (unsigned)a00[kt][r]
                             + (((unsigned)a01[kt][r] + (unsigned)a10[kt][r]) << 8)
                             + ((unsigned)a11[kt][r] << 16)
                             + qq + offv[kt][r];
                out[ob + (long)r * 3136] = (int)val;
            }
        }
    }
}

extern "C" void kernel_launch(void* const* d_in, const int* in_sizes, int n_in,
                              void* d_out, int out_size, void* d_ws, size_t ws_size,
                              hipStream_t stream)
{
    const int* x    = (const int*)d_in[0];
    const int* w    = (const int*)d_in[1];
    const int* bias = (const int*)d_in[2];
    int* out        = (int*)d_out;

    packx  <<<dim3(421), dim3(256), 0, stream>>>(x);
    packw  <<<dim3(145), dim3(256), 0, stream>>>(w, bias);
    secconv<<<dim3(896), dim3(256), 0, stream>>>(out);
}

// Round 8
// 108.654 us; speedup vs baseline: 1.0991x; 1.0991x over previous
//
#include <hip/hip_runtime.h>

// SecConv2d over Z_{2^32} via i8 MFMA, 4-chain biased-operand scheme (exact).
//   s(x) = x_byte - 128 per limb  => X = s(al) + 256*s(ah) + 32896
//   s(w) likewise                 => W = s0 + 256*s1 + 32896
//   out = P00 + (P01+P10)<<8 + P11<<16 + 32896*Q[p] + K[k]   (mod 2^32)
//   Q = 3x3 box sum of S[p], S[p] = sum_c (X_true - 32896) (border: X_true=0,
//   border bytes 0x80 == s=-128 -> uniformly "interior with x=0", exact).
//
// R8: packx is FUSED into secconv. Each block (2 out rows x 56 cols, 64 kout)
// reads its 4 raw input rows, transposes to channel-minor bytes in-register
// (v_perm_b32), accumulates the channel sum with v_sad_u8, writes LDS once.
// One barrier, then the R7 MFMA phase (2 ktiles/wave resident, 4 chains).

typedef int v4i __attribute__((ext_vector_type(4)));

#define LCOL 144               // LDS col stride (128 B payload + 16 pad)
#define LROW (58 * LCOL)       // 8352 B per LDS halo row

__device__ __align__(16) unsigned char g_wb[2 * 9 * 64 * 64];
__device__ unsigned g_off[64];

static __device__ __forceinline__ unsigned bsum(unsigned v, unsigned acc) {
#if __has_builtin(__builtin_amdgcn_sad_u8)
    return __builtin_amdgcn_sad_u8(v, 0u, acc);
#else
    return acc + (v & 0xFFu) + ((v >> 8) & 0xFFu) + ((v >> 16) & 0xFFu) + (v >> 24);
#endif
}

__global__ __launch_bounds__(256) void packw(const int* __restrict__ w,
                                             const int* __restrict__ bias) {
    int blk = blockIdx.x;
    if (blk < 144) {
        int i = blk * 256 + threadIdx.x;        // [k][c][t] flat, 36864
        if (i >= 64 * 64 * 9) return;
        int k = i / 576;
        int r = i - k * 576;
        int c = r / 9;
        int t = r - c * 9;
        unsigned v = (unsigned)w[i];
        g_wb[((0 * 9 + t) * 64 + k) * 64 + c] = (unsigned char)((v & 255u) ^ 0x80u);
        g_wb[((1 * 9 + t) * 64 + k) * 64 + c] = (unsigned char)(((v >> 8) & 255u) ^ 0x80u);
    } else if (threadIdx.x < 64) {
        int k = threadIdx.x;
        int s0 = 0, s1 = 0;
        for (int j = 0; j < 576; ++j) {
            unsigned W = (unsigned)w[k * 576 + j];
            s0 += (int)(W & 255u);
            s1 += (int)((W >> 8) & 255u);
        }
        s0 -= 73728;                     // -128*576
        s1 -= 73728;
        unsigned ws = (unsigned)(s0 + 256 * s1);
        g_off[k] = (unsigned)bias[k] + 32896u * ws + 1082146816u * 576u;
    }
}

__global__ __launch_bounds__(256, 2) void secconv(const int* __restrict__ x,
                                                  int* __restrict__ out)
{
    __shared__ unsigned char sx[4 * LROW];      // 33408 B
    __shared__ int ss[232];                     // S-plane, 4 rows x 58

    const int tid  = threadIdx.x;
    const int blk  = blockIdx.x;                // 896 = 8 xcd * 112
    const int q    = blk >> 3;
    const int rp   = q % 28;                    // output row-pair
    const int n    = (blk & 7) + 8 * (q / 28);
    const int wid  = tid >> 6;
    const int lane = tid & 63;
    const int lm   = lane & 15;
    const int lq   = lane >> 4;
    const int kp   = wid & 1;
    const int ph   = wid >> 1;
    const int kbase = kp * 32;

    // ---- fused pack: thread -> one halo pixel; transpose 64 ch to bytes ----
    if (tid < 232) {
        const int pr = tid / 58, pc = tid - pr * 58;
        const int ih = 2 * rp - 1 + pr, iw = pc - 1;
        unsigned char* ob = sx + pr * LROW + pc * LCOL;
        int S;
        if ((unsigned)ih < 56u && (unsigned)iw < 56u) {
            const int* xp = x + (long)n * 64 * 3136 + ih * 56 + iw;
            unsigned slo = 0, shi = 0;
#pragma unroll
            for (int g = 0; g < 4; ++g) {       // 4 groups of 16 channels
                unsigned lo[4], hi[4];
#pragma unroll
                for (int u = 0; u < 4; ++u) {
                    const int c = g * 16 + u * 4;
                    unsigned v0 = (unsigned)xp[(c + 0) * 3136];
                    unsigned v1 = (unsigned)xp[(c + 1) * 3136];
                    unsigned v2 = (unsigned)xp[(c + 2) * 3136];
                    unsigned v3 = (unsigned)xp[(c + 3) * 3136];
                    unsigned t01 = __builtin_amdgcn_perm(v1, v0, 0x05040100u);
                    unsigned t23 = __builtin_amdgcn_perm(v3, v2, 0x05040100u);
                    unsigned lw  = __builtin_amdgcn_perm(t23, t01, 0x06040200u);
                    unsigned hw  = __builtin_amdgcn_perm(t23, t01, 0x07050301u);
                    slo = bsum(lw, slo);
                    shi = bsum(hw, shi);
                    lo[u] = lw ^ 0x80808080u;
                    hi[u] = hw ^ 0x80808080u;
                }
                *(uint4*)(ob + g * 16)      = make_uint4(lo[0], lo[1], lo[2], lo[3]);
                *(uint4*)(ob + 64 + g * 16) = make_uint4(hi[0], hi[1], hi[2], hi[3]);
            }
            S = (int)(slo + (shi << 8)) - 2105344;   // -64*32896
        } else {
            uint4 v = make_uint4(0x80808080u, 0x80808080u, 0x80808080u, 0x80808080u);
#pragma unroll
            for (int g = 0; g < 4; ++g) {
                *(uint4*)(ob + g * 16)      = v;
                *(uint4*)(ob + 64 + g * 16) = v;
            }
            S = -2105344;
        }
        ss[tid] = S;
    }

    // ---- resident weight fragments: 2 ktiles x 2 limbs x 9 taps ----
    v4i wf[2][2][9];
#pragma unroll
    for (int kt = 0; kt < 2; ++kt)
#pragma unroll
        for (int l = 0; l < 2; ++l)
#pragma unroll
            for (int t = 0; t < 9; ++t)
                wf[kt][l][t] = *(const v4i*)(g_wb +
                    ((l * 9 + t) * 64 + (kbase + kt * 16 + lm)) * 64 + lq * 16);
    unsigned offv[2][4];
#pragma unroll
    for (int kt = 0; kt < 2; ++kt)
#pragma unroll
        for (int r = 0; r < 4; ++r)
            offv[kt][r] = g_off[kbase + kt * 16 + lq * 4 + r];

    __syncthreads();

    const int r8 = lm >> 3, c8 = lm & 7;        // pixel tile: 2 rows x 8 cols
    const unsigned char* lbase = sx + r8 * LROW + c8 * LCOL + lq * 16;

    const int t0 = ph ? 4 : 0, t1 = ph ? 7 : 4;
    for (int t = t0; t < t1; ++t) {
        const unsigned char* tb = lbase + t * 8 * LCOL;
        v4i a00[2] = {{0,0,0,0},{0,0,0,0}}, a01[2] = {{0,0,0,0},{0,0,0,0}};
        v4i a10[2] = {{0,0,0,0},{0,0,0,0}}, a11[2] = {{0,0,0,0},{0,0,0,0}};
#pragma unroll
        for (int tap = 0; tap < 9; ++tap) {
            const int dr = tap / 3, dc = tap - (tap / 3) * 3;
            const unsigned char* pp = tb + dr * LROW + dc * LCOL;
            v4i bl = *(const v4i*)(pp);
            v4i bh = *(const v4i*)(pp + 64);
#pragma unroll
            for (int kt = 0; kt < 2; ++kt) {
                a00[kt] = __builtin_amdgcn_mfma_i32_16x16x64_i8(wf[kt][0][tap], bl, a00[kt], 0, 0, 0);
                a01[kt] = __builtin_amdgcn_mfma_i32_16x16x64_i8(wf[kt][0][tap], bh, a01[kt], 0, 0, 0);
                a10[kt] = __builtin_amdgcn_mfma_i32_16x16x64_i8(wf[kt][1][tap], bl, a10[kt], 0, 0, 0);
                a11[kt] = __builtin_amdgcn_mfma_i32_16x16x64_i8(wf[kt][1][tap], bh, a11[kt], 0, 0, 0);
            }
        }

        const int pc = t * 8 + c8;
        int Q = 0;
#pragma unroll
        for (int dr = 0; dr < 3; ++dr)
#pragma unroll
            for (int dc = 0; dc < 3; ++dc)
                Q += ss[(r8 + dr) * 58 + pc + dc];
        const unsigned qq = 32896u * (unsigned)Q;

        const long pix = (long)(2 * rp + r8) * 56 + pc;
#pragma unroll
        for (int kt = 0; kt < 2; ++kt) {
            const long ob = ((long)n * 64 + kbase + kt * 16 + lq * 4) * 3136 + pix;
#pragma unroll
            for (int r = 0; r < 4; ++r) {
                unsigned val = (unsigned)a00[kt][r]
                             + (((unsigned)a01[kt][r] + (unsigned)a10[kt][r]) << 8)
                             + ((unsigned)a11[kt][r] << 16)
                             + qq + offv[kt][r];
                out[ob + (long)r * 3136] = (int)val;
            }
        }
    }
}

extern "C" void kernel_launch(void* const* d_in, const int* in_sizes, int n_in,
                              void* d_out, int out_size, void* d_ws, size_t ws_size,
                              hipStream_t stream)
{
    const int* x    = (const int*)d_in[0];
    const int* w    = (const int*)d_in[1];
    const int* bias = (const int*)d_in[2];
    int* out        = (int*)d_out;

    packw  <<<dim3(145), dim3(256), 0, stream>>>(w, bias);
    secconv<<<dim3(896), dim3(256), 0, stream>>>(x, out);
}

// Round 9
// 98.572 us; speedup vs baseline: 1.2115x; 1.1023x over previous
//
#include <hip/hip_runtime.h>

// SecConv2d over Z_{2^32} via i8 MFMA, 4-chain biased-operand scheme (exact).
//   s(x) = x_byte - 128 per limb  => X = s(al) + 256*s(ah) + 32896
//   s(w) likewise                 => W = s0 + 256*s1 + 32896
//   out = P00 + (P01+P10)<<8 + P11<<16 + 32896*Q[p] + K[k]   (mod 2^32)
//   Q = 3x3 box sum of S[p], S[p] = sum_c (X_true - 32896) (border cells are
//   bytes 0x80 == s=-128 -> uniformly "interior with x=0", exact).
//
// R9: block = 4 output rows x 56 cols (14 pixel-tiles), 4 waves =
// (ktile-pair kp x row-pair ph). 448 blocks at 2/CU -> all co-resident in
// ONE round (no tail). Staging redundancy 1.5x (6 halo rows / 4 out rows).
// packw offset reduction parallelized (4 thr/k + shfl_xor).

typedef int v4i __attribute__((ext_vector_type(4)));

#define LCOL 144               // LDS col stride (128 B payload + 16 pad)
#define LROW (58 * LCOL)       // 8352 B per LDS halo row

__device__ __align__(16) unsigned char g_wb[2 * 9 * 64 * 64];
__device__ unsigned g_off[64];

static __device__ __forceinline__ unsigned bsum(unsigned v, unsigned acc) {
#if __has_builtin(__builtin_amdgcn_sad_u8)
    return __builtin_amdgcn_sad_u8(v, 0u, acc);
#else
    return acc + (v & 0xFFu) + ((v >> 8) & 0xFFu) + ((v >> 16) & 0xFFu) + (v >> 24);
#endif
}

__global__ __launch_bounds__(256) void packw(const int* __restrict__ w,
                                             const int* __restrict__ bias) {
    int blk = blockIdx.x;
    if (blk < 144) {
        int i = blk * 256 + threadIdx.x;        // [k][c][t] flat, 36864
        if (i >= 64 * 64 * 9) return;
        int k = i / 576;
        int r = i - k * 576;
        int c = r / 9;
        int t = r - c * 9;
        unsigned v = (unsigned)w[i];
        g_wb[((0 * 9 + t) * 64 + k) * 64 + c] = (unsigned char)((v & 255u) ^ 0x80u);
        g_wb[((1 * 9 + t) * 64 + k) * 64 + c] = (unsigned char)(((v >> 8) & 255u) ^ 0x80u);
    } else {
        int k    = threadIdx.x >> 2;            // 4 threads per k
        int part = threadIdx.x & 3;
        int s0 = 0, s1 = 0;
        for (int j = part * 144; j < part * 144 + 144; ++j) {
            unsigned W = (unsigned)w[k * 576 + j];
            s0 += (int)(W & 255u);
            s1 += (int)((W >> 8) & 255u);
        }
        s0 += __shfl_xor(s0, 1); s0 += __shfl_xor(s0, 2);
        s1 += __shfl_xor(s1, 1); s1 += __shfl_xor(s1, 2);
        if (part == 0) {
            s0 -= 73728;                        // -128*576
            s1 -= 73728;
            unsigned ws = (unsigned)(s0 + 256 * s1);
            g_off[k] = (unsigned)bias[k] + 32896u * ws + 1082146816u * 576u;
        }
    }
}

__global__ __launch_bounds__(256, 2) void secconv(const int* __restrict__ x,
                                                  int* __restrict__ out)
{
    __shared__ unsigned char sx[6 * LROW];      // 50112 B
    __shared__ int ss[6 * 58];                  // S-plane, 6 halo rows

    const int tid  = threadIdx.x;
    const int blk  = blockIdx.x;                // 448 = 8 xcd * 56
    const int q    = blk >> 3;
    const int rg   = q % 14;                    // row-group of 4 output rows
    const int n    = (blk & 7) + 8 * (q / 14);
    const int wid  = tid >> 6;
    const int lane = tid & 63;
    const int lm   = lane & 15;
    const int lq   = lane >> 4;
    const int kp   = wid & 1;                   // ktile-pair -> k base kp*32
    const int ph   = wid >> 1;                  // row-pair within the 4 rows
    const int kbase = kp * 32;

    // ---- fused pack: 348 halo pixels; transpose 64 ch to bytes ----
    for (int it = tid; it < 348; it += 256) {
        const int pr = it / 58, pc = it - pr * 58;
        const int ih = 4 * rg - 1 + pr, iw = pc - 1;
        unsigned char* ob = sx + pr * LROW + pc * LCOL;
        int S;
        if ((unsigned)ih < 56u && (unsigned)iw < 56u) {
            const int* xp = x + (long)n * 64 * 3136 + ih * 56 + iw;
            unsigned slo = 0, shi = 0;
#pragma unroll
            for (int g = 0; g < 4; ++g) {       // 4 groups of 16 channels
                unsigned lo[4], hi[4];
#pragma unroll
                for (int u = 0; u < 4; ++u) {
                    const int c = g * 16 + u * 4;
                    unsigned v0 = (unsigned)xp[(c + 0) * 3136];
                    unsigned v1 = (unsigned)xp[(c + 1) * 3136];
                    unsigned v2 = (unsigned)xp[(c + 2) * 3136];
                    unsigned v3 = (unsigned)xp[(c + 3) * 3136];
                    unsigned t01 = __builtin_amdgcn_perm(v1, v0, 0x05040100u);
                    unsigned t23 = __builtin_amdgcn_perm(v3, v2, 0x05040100u);
                    unsigned lw  = __builtin_amdgcn_perm(t23, t01, 0x06040200u);
                    unsigned hw  = __builtin_amdgcn_perm(t23, t01, 0x07050301u);
                    slo = bsum(lw, slo);
                    shi = bsum(hw, shi);
                    lo[u] = lw ^ 0x80808080u;
                    hi[u] = hw ^ 0x80808080u;
                }
                *(uint4*)(ob + g * 16)      = make_uint4(lo[0], lo[1], lo[2], lo[3]);
                *(uint4*)(ob + 64 + g * 16) = make_uint4(hi[0], hi[1], hi[2], hi[3]);
            }
            S = (int)(slo + (shi << 8)) - 2105344;   // -64*32896
        } else {
            uint4 v = make_uint4(0x80808080u, 0x80808080u, 0x80808080u, 0x80808080u);
#pragma unroll
            for (int g = 0; g < 4; ++g) {
                *(uint4*)(ob + g * 16)      = v;
                *(uint4*)(ob + 64 + g * 16) = v;
            }
            S = -2105344;
        }
        ss[it] = S;
    }

    // ---- resident weight fragments: 2 ktiles x 2 limbs x 9 taps ----
    v4i wf[2][2][9];
#pragma unroll
    for (int kt = 0; kt < 2; ++kt)
#pragma unroll
        for (int l = 0; l < 2; ++l)
#pragma unroll
            for (int t = 0; t < 9; ++t)
                wf[kt][l][t] = *(const v4i*)(g_wb +
                    ((l * 9 + t) * 64 + (kbase + kt * 16 + lm)) * 64 + lq * 16);
    unsigned offv[2][4];
#pragma unroll
    for (int kt = 0; kt < 2; ++kt)
#pragma unroll
        for (int r = 0; r < 4; ++r)
            offv[kt][r] = g_off[kbase + kt * 16 + lq * 4 + r];

    __syncthreads();

    const int r8 = lm >> 3, c8 = lm & 7;        // pixel tile: 2 rows x 8 cols
    const int lrow = 2 * ph + r8;               // LDS halo row of this lane
    const unsigned char* lbase = sx + lrow * LROW + c8 * LCOL + lq * 16;

    for (int t = 0; t < 7; ++t) {               // 7 col-groups of 8
        const unsigned char* tb = lbase + t * 8 * LCOL;
        v4i a00[2] = {{0,0,0,0},{0,0,0,0}}, a01[2] = {{0,0,0,0},{0,0,0,0}};
        v4i a10[2] = {{0,0,0,0},{0,0,0,0}}, a11[2] = {{0,0,0,0},{0,0,0,0}};
#pragma unroll
        for (int tap = 0; tap < 9; ++tap) {
            const int dr = tap / 3, dc = tap - (tap / 3) * 3;
            const unsigned char* pp = tb + dr * LROW + dc * LCOL;
            v4i bl = *(const v4i*)(pp);
            v4i bh = *(const v4i*)(pp + 64);
#pragma unroll
            for (int kt = 0; kt < 2; ++kt) {
                a00[kt] = __builtin_amdgcn_mfma_i32_16x16x64_i8(wf[kt][0][tap], bl, a00[kt], 0, 0, 0);
                a01[kt] = __builtin_amdgcn_mfma_i32_16x16x64_i8(wf[kt][0][tap], bh, a01[kt], 0, 0, 0);
                a10[kt] = __builtin_amdgcn_mfma_i32_16x16x64_i8(wf[kt][1][tap], bl, a10[kt], 0, 0, 0);
                a11[kt] = __builtin_amdgcn_mfma_i32_16x16x64_i8(wf[kt][1][tap], bh, a11[kt], 0, 0, 0);
            }
        }

        const int pc = t * 8 + c8;
        int Q = 0;
#pragma unroll
        for (int dr = 0; dr < 3; ++dr)
#pragma unroll
            for (int dc = 0; dc < 3; ++dc)
                Q += ss[(lrow + dr) * 58 + pc + dc];
        const unsigned qq = 32896u * (unsigned)Q;

        const long pix = (long)(4 * rg + lrow) * 56 + pc;
#pragma unroll
        for (int kt = 0; kt < 2; ++kt) {
            const long ob = ((long)n * 64 + kbase + kt * 16 + lq * 4) * 3136 + pix;
#pragma unroll
            for (int r = 0; r < 4; ++r) {
                unsigned val = (unsigned)a00[kt][r]
                             + (((unsigned)a01[kt][r] + (unsigned)a10[kt][r]) << 8)
                             + ((unsigned)a11[kt][r] << 16)
                             + qq + offv[kt][r];
                out[ob + (long)r * 3136] = (int)val;
            }
        }
    }
}

extern "C" void kernel_launch(void* const* d_in, const int* in_sizes, int n_in,
                              void* d_out, int out_size, void* d_ws, size_t ws_size,
                              hipStream_t stream)
{
    const int* x    = (const int*)d_in[0];
    const int* w    = (const int*)d_in[1];
    const int* bias = (const int*)d_in[2];
    int* out        = (int*)d_out;

    packw  <<<dim3(145), dim3(256), 0, stream>>>(w, bias);
    secconv<<<dim3(448), dim3(256), 0, stream>>>(x, out);
}